// Round 6
// baseline (1499.636 us; speedup 1.0000x reference)
//
#include <hip/hip_runtime.h>

#define T_STEPS 512
#define BC      4       // batch columns per block
#define BLOCK   576     // 9 waves

// ---------------------------------------------------------------------------
// Fused-GRU tick: ONE barrier per tick, zero gate LDS traffic.
//
// R5 post-mortem: tick = 1.94us with VALUBusy 31% at 2 waves/SIMD -> ~70%
// stall; the critical path was G -> gate-LDS write -> barrier -> U gate-LDS
// read -> transcendentals -> h write -> barrier. This version fuses: each
// lane accumulates r,z,inn,hn for its gate-row triple (ih+hh share the r/z
// accumulators), butterflies 16 values, and the kci==0 owner applies the
// nonlinearity and writes h' straight to LDS. Double-buffered h and x make
// read(cur)/write(nxt) race-free with a single barrier.
//
//   wave  section                    shape    KC  tid        thr  fmaf
//   W0-3  l0 (Kih64 Khh32, H32)      <8,4>    8     0-255    256  144
//   W4-5  l4 (16,32, H32)            <4,8>    4   256-383    128  144
//   W6    l1 (32,16, H16)            <8,4>    4   384-447     64  144
//   W7    out (K32) + x-prefetch      --      1   448-511     64  128
//   W8    l3 (8,16,H16) KC2 lanes0-31 <4,8>   rt  512-575   32+32 144
//         l2 (16,8->pad32,H8) KC4 lanes32-63
//
// l2 hh zero-padding: shape <4,8> KC4 covers 32 hh cols but Khh=8; h2 rows
// 8-31 are zeroed at init and never written (owners write hrow<H only);
// load_lw zeroes the matching weights. Butterfly groups are KC-aligned and
// never straddle sections; W8's if(KC>2) level runs only on the aligned
// l2 half (partners stay inside lanes 32-63).
//
// Read swizzle: col = kci*S + (kk ^ (kci & (S-1))) -> 16B granules distinct
// (S=8) or <=2-way (S=4, free per m136) across kci at each kk step.
//
// sm layout (floats): x[2][64][4] @0..512 | h[2][5][32][4] @512..1792
// = 7168 B LDS. Skew: at tick tau layer l computes t=tau-l (window
// [l, l+511]), out-proj t=tau-5 ([5,516]); all reads hit parity cur=tau&1,
// all writes hit parity cur^1.
// ---------------------------------------------------------------------------

__device__ __forceinline__ float sigmoid_f(float x) {
    return 1.0f / (1.0f + __expf(-x));
}
__device__ __forceinline__ float tanh_f(float x) {
    return 1.0f - 2.0f / (__expf(2.0f * x) + 1.0f);
}

// Weight loader: gate-row triple (r=h, z=H+h, n=2H+h) of Wih/Whh, swizzled
// to match the gemm read order. Compile-time indexing only (rule #20).
// wr layout: [0..S) w_r (ih|hh), [S..2S) w_z, [2S..2S+SIH) w_ni,
//            [2S+SIH..3S) w_nh.   S = SIH+SHH = 12, total 36.
template<int SIH, int SHH>
__device__ __forceinline__ void load_lw(float (&wr)[36], float (&bs)[4],
                                        const float* __restrict__ Wi,
                                        const float* __restrict__ Wh,
                                        const float* __restrict__ Bi,
                                        const float* __restrict__ Bh,
                                        int h, int H, int Kih, int Khh, int kci)
{
    constexpr int S = SIH + SHH;
#pragma unroll
    for (int kk = 0; kk < SIH; ++kk) {
        const int col = kci * SIH + (kk ^ (kci & (SIH - 1)));
        const bool ok = (col < Kih);
        wr[kk]         = ok ? Wi[h * Kih + col]           : 0.0f;
        wr[S + kk]     = ok ? Wi[(H + h) * Kih + col]     : 0.0f;
        wr[2 * S + kk] = ok ? Wi[(2 * H + h) * Kih + col] : 0.0f;
    }
#pragma unroll
    for (int kk = 0; kk < SHH; ++kk) {
        const int col = kci * SHH + (kk ^ (kci & (SHH - 1)));
        const bool ok = (col < Khh);
        wr[SIH + kk]           = ok ? Wh[h * Khh + col]           : 0.0f;
        wr[S + SIH + kk]       = ok ? Wh[(H + h) * Khh + col]     : 0.0f;
        wr[2 * S + SIH + kk]   = ok ? Wh[(2 * H + h) * Khh + col] : 0.0f;
    }
    bs[0] = Bi[h] + Bh[h];                  // r bias (merged)
    bs[1] = Bi[H + h] + Bh[H + h];          // z bias (merged)
    bs[2] = Bi[2 * H + h];                  // n bias, ih part
    bs[3] = Bh[2 * H + h];                  // n bias, hh part
}

// Fused layer tick: dot + butterfly + nonlinearity + h write.
template<int SIH, int SHH>
__device__ __forceinline__ void layer_f(const float (&wr)[36], const float (&bs)[4],
                                        int kci, int KC, float* __restrict__ sm,
                                        int inb, int hb, int wb, int hrow)
{
    constexpr int S = SIH + SHH;
    const bool own = (kci == 0);
    float ar[4], az[4], ani[4], anh[4];
#pragma unroll
    for (int b = 0; b < 4; ++b) {
        ar[b]  = own ? bs[0] : 0.0f;
        az[b]  = own ? bs[1] : 0.0f;
        ani[b] = own ? bs[2] : 0.0f;
        anh[b] = own ? bs[3] : 0.0f;
    }
#pragma unroll
    for (int kk = 0; kk < SIH; ++kk) {
        const int col = kci * SIH + (kk ^ (kci & (SIH - 1)));
        const float4 v = *(const float4*)&sm[inb + col * 4];
        const float w0 = wr[kk], w1 = wr[S + kk], w2 = wr[2 * S + kk];
        ar[0]  = fmaf(w0, v.x, ar[0]);  ar[1]  = fmaf(w0, v.y, ar[1]);
        ar[2]  = fmaf(w0, v.z, ar[2]);  ar[3]  = fmaf(w0, v.w, ar[3]);
        az[0]  = fmaf(w1, v.x, az[0]);  az[1]  = fmaf(w1, v.y, az[1]);
        az[2]  = fmaf(w1, v.z, az[2]);  az[3]  = fmaf(w1, v.w, az[3]);
        ani[0] = fmaf(w2, v.x, ani[0]); ani[1] = fmaf(w2, v.y, ani[1]);
        ani[2] = fmaf(w2, v.z, ani[2]); ani[3] = fmaf(w2, v.w, ani[3]);
    }
#pragma unroll
    for (int kk = 0; kk < SHH; ++kk) {
        const int col = kci * SHH + (kk ^ (kci & (SHH - 1)));
        const float4 v = *(const float4*)&sm[hb + col * 4];
        const float w0 = wr[SIH + kk], w1 = wr[S + SIH + kk], w2 = wr[2 * S + SIH + kk];
        ar[0]  = fmaf(w0, v.x, ar[0]);  ar[1]  = fmaf(w0, v.y, ar[1]);
        ar[2]  = fmaf(w0, v.z, ar[2]);  ar[3]  = fmaf(w0, v.w, ar[3]);
        az[0]  = fmaf(w1, v.x, az[0]);  az[1]  = fmaf(w1, v.y, az[1]);
        az[2]  = fmaf(w1, v.z, az[2]);  az[3]  = fmaf(w1, v.w, az[3]);
        anh[0] = fmaf(w2, v.x, anh[0]); anh[1] = fmaf(w2, v.y, anh[1]);
        anh[2] = fmaf(w2, v.z, anh[2]); anh[3] = fmaf(w2, v.w, anh[3]);
    }
    if (KC > 1) {
#pragma unroll
        for (int b = 0; b < 4; ++b) {
            ar[b]  += __shfl_xor(ar[b],  1, 64);
            az[b]  += __shfl_xor(az[b],  1, 64);
            ani[b] += __shfl_xor(ani[b], 1, 64);
            anh[b] += __shfl_xor(anh[b], 1, 64);
        }
    }
    if (KC > 2) {
#pragma unroll
        for (int b = 0; b < 4; ++b) {
            ar[b]  += __shfl_xor(ar[b],  2, 64);
            az[b]  += __shfl_xor(az[b],  2, 64);
            ani[b] += __shfl_xor(ani[b], 2, 64);
            anh[b] += __shfl_xor(anh[b], 2, 64);
        }
    }
    if (KC > 4) {
#pragma unroll
        for (int b = 0; b < 4; ++b) {
            ar[b]  += __shfl_xor(ar[b],  4, 64);
            az[b]  += __shfl_xor(az[b],  4, 64);
            ani[b] += __shfl_xor(ani[b], 4, 64);
            anh[b] += __shfl_xor(anh[b], 4, 64);
        }
    }
    if (own) {
        const float4 hp = *(const float4*)&sm[hb + hrow * 4];
        float4 hn;
        {
            const float r = sigmoid_f(ar[0]), z = sigmoid_f(az[0]);
            const float n = tanh_f(fmaf(r, anh[0], ani[0]));
            hn.x = (1.0f - z) * n + z * hp.x;
        }
        {
            const float r = sigmoid_f(ar[1]), z = sigmoid_f(az[1]);
            const float n = tanh_f(fmaf(r, anh[1], ani[1]));
            hn.y = (1.0f - z) * n + z * hp.y;
        }
        {
            const float r = sigmoid_f(ar[2]), z = sigmoid_f(az[2]);
            const float n = tanh_f(fmaf(r, anh[2], ani[2]));
            hn.z = (1.0f - z) * n + z * hp.z;
        }
        {
            const float r = sigmoid_f(ar[3]), z = sigmoid_f(az[3]);
            const float n = tanh_f(fmaf(r, anh[3], ani[3]));
            hn.w = (1.0f - z) * n + z * hp.w;
        }
        *(float4*)&sm[wb + hrow * 4] = hn;
    }
}

// Out-projection: one row, full K=32 dot (broadcast reads), 4 coalesced stores.
__device__ __forceinline__ void out_f(const float (&wr)[36], float bo, int orow,
                                      const float* __restrict__ sm, int hb4,
                                      float* __restrict__ outp)
{
    float a[4] = {bo, bo, bo, bo};
#pragma unroll
    for (int kk = 0; kk < 32; ++kk) {
        const float4 v = *(const float4*)&sm[hb4 + kk * 4];
        const float w = wr[kk];
        a[0] = fmaf(w, v.x, a[0]); a[1] = fmaf(w, v.y, a[1]);
        a[2] = fmaf(w, v.z, a[2]); a[3] = fmaf(w, v.w, a[3]);
    }
#pragma unroll
    for (int b = 0; b < 4; ++b)
        outp[(size_t)b * (T_STEPS * 64) + orow] = a[b];
}

__global__ __launch_bounds__(BLOCK, 1)
void gru_kernel(const float* __restrict__ X,
                const float* wih0, const float* whh0, const float* bih0, const float* bhh0,
                const float* wih1, const float* whh1, const float* bih1, const float* bhh1,
                const float* wih2, const float* whh2, const float* bih2, const float* bhh2,
                const float* wih3, const float* whh3, const float* bih3, const float* bhh3,
                const float* wih4, const float* whh4, const float* bih4, const float* bhh4,
                const float* wout, const float* bout,
                float* __restrict__ out)
{
    __shared__ __align__(16) float sm[1792];   // x[2][64][4] | h[2][5][32][4]

    const int tid = threadIdx.x;
    const int b0  = blockIdx.x * BC;

    float wr[36];
    float bs[4];

    // ---- per-lane section parameters ----
    int lay = 0, hrow = 0, kci = 0, KC = 1, lo = 0, Kih = 0, Khh = 0, Hh = 0;
    int orow = 0;
    const float *Wi = nullptr, *Wh = nullptr, *Bi = nullptr, *Bh = nullptr;

    if (tid < 256) {            // l0
        lay = 0; hrow = tid >> 3; kci = tid & 7; KC = 8;
        Kih = 64; Khh = 32; Hh = 32; lo = 0;
        Wi = wih0; Wh = whh0; Bi = bih0; Bh = bhh0;
    } else if (tid < 384) {     // l4
        const int t = tid - 256;
        lay = 4; hrow = t >> 2; kci = t & 3; KC = 4;
        Kih = 16; Khh = 32; Hh = 32; lo = 4;
        Wi = wih4; Wh = whh4; Bi = bih4; Bh = bhh4;
    } else if (tid < 448) {     // l1
        const int t = tid - 384;
        lay = 1; hrow = t >> 2; kci = t & 3; KC = 4;
        Kih = 32; Khh = 16; Hh = 16; lo = 1;
        Wi = wih1; Wh = whh1; Bi = bih1; Bh = bhh1;
    } else if (tid < 512) {     // out-proj + x-prefetch
        orow = tid - 448; lo = 5;
    } else if (tid < 544) {     // l3
        const int t = tid - 512;
        lay = 3; hrow = t >> 1; kci = t & 1; KC = 2;
        Kih = 8; Khh = 16; Hh = 16; lo = 3;
        Wi = wih3; Wh = whh3; Bi = bih3; Bh = bhh3;
    } else {                    // l2 (hh zero-padded 8->32)
        const int t = tid - 544;
        lay = 2; hrow = t >> 2; kci = t & 3; KC = 4;
        Kih = 16; Khh = 8; Hh = 8; lo = 2;
        Wi = wih2; Wh = whh2; Bi = bih2; Bh = bhh2;
    }
    const int hi = lo + 511;

    // ---- weights -> registers (shape-matched loader per wave) ----
    if (tid < 256)      load_lw<8, 4>(wr, bs, Wi, Wh, Bi, Bh, hrow, Hh, Kih, Khh, kci);
    else if (tid < 384) load_lw<4, 8>(wr, bs, Wi, Wh, Bi, Bh, hrow, Hh, Kih, Khh, kci);
    else if (tid < 448) load_lw<8, 4>(wr, bs, Wi, Wh, Bi, Bh, hrow, Hh, Kih, Khh, kci);
    else if (tid < 512) {
#pragma unroll
        for (int kk = 0; kk < 32; ++kk) wr[kk] = wout[orow * 32 + kk];
        bs[0] = bout[orow];
    }
    else                load_lw<4, 8>(wr, bs, Wi, Wh, Bi, Bh, hrow, Hh, Kih, Khh, kci);

    // ---- per-lane parity-dependent LDS bases ----
    const int inbE = (lay == 0) ? 0 : 512 + (lay - 1) * 128;
    const int inbO = inbE + ((lay == 0) ? 256 : 640);
    const int hbE  = 512 + lay * 128;
    const int hbO  = hbE + 640;

    // ---- init: zero both h buffers (incl. padding rows), stage x(0) ----
    for (int i = 512 + tid; i < 1792; i += BLOCK) sm[i] = 0.0f;
    if (tid >= 448 && tid < 512) {
        const int e = tid - 448, xb = e & 3, xd0 = (e >> 2) << 2;
        const float4 v = *(const float4*)&X[(size_t)(b0 + xb) * (T_STEPS * 64) + xd0];
        sm[(xd0 + 0) * 4 + xb] = v.x; sm[(xd0 + 1) * 4 + xb] = v.y;
        sm[(xd0 + 2) * 4 + xb] = v.z; sm[(xd0 + 3) * 4 + xb] = v.w;
    }
    __syncthreads();

    for (int tau = 0; tau < T_STEPS + 5; ++tau) {
        const int cur = tau & 1;
        const bool act = (tau >= lo) && (tau <= hi);

        if (tid < 448) {
            if (act) {
                const int inb = cur ? inbO : inbE;
                const int hb  = cur ? hbO  : hbE;
                const int wb  = cur ? hbE  : hbO;     // write other parity
                if (tid < 256)      layer_f<8, 4>(wr, bs, kci, KC, sm, inb, hb, wb, hrow);
                else if (tid < 384) layer_f<4, 8>(wr, bs, kci, KC, sm, inb, hb, wb, hrow);
                else                layer_f<8, 4>(wr, bs, kci, KC, sm, inb, hb, wb, hrow);
            }
        } else if (tid < 512) {
            float4 xr = {0.f, 0.f, 0.f, 0.f};
            const bool pf = (tau + 1 < T_STEPS);
            const int e = tid - 448, xb = e & 3, xd0 = (e >> 2) << 2;
            if (pf)
                xr = *(const float4*)&X[((size_t)(b0 + xb) * T_STEPS + (tau + 1)) * 64 + xd0];
            if (act)
                out_f(wr, bs[0], orow, sm, cur ? 1664 : 1024,
                      out + ((size_t)b0 * T_STEPS + (tau - 5)) * 64);
            if (pf) {
                const int xw = (cur ^ 1) * 256;
                sm[xw + (xd0 + 0) * 4 + xb] = xr.x; sm[xw + (xd0 + 1) * 4 + xb] = xr.y;
                sm[xw + (xd0 + 2) * 4 + xb] = xr.z; sm[xw + (xd0 + 3) * 4 + xb] = xr.w;
            }
        } else {
            if (act) {
                const int inb = cur ? inbO : inbE;
                const int hb  = cur ? hbO  : hbE;
                const int wb  = cur ? hbE  : hbO;
                layer_f<4, 8>(wr, bs, kci, KC, sm, inb, hb, wb, hrow);
            }
        }
        __syncthreads();
    }
}

extern "C" void kernel_launch(void* const* d_in, const int* in_sizes, int n_in,
                              void* d_out, int out_size, void* d_ws, size_t ws_size,
                              hipStream_t stream)
{
    const float* X = (const float*)d_in[0];
    const float* wih[5]; const float* whh[5]; const float* bih[5]; const float* bhh[5];
    for (int l = 0; l < 5; ++l) {
        wih[l] = (const float*)d_in[1 + 4 * l];
        whh[l] = (const float*)d_in[2 + 4 * l];
        bih[l] = (const float*)d_in[3 + 4 * l];
        bhh[l] = (const float*)d_in[4 + 4 * l];
    }
    const float* wout = (const float*)d_in[21];
    const float* bout = (const float*)d_in[22];

    gru_kernel<<<1024 / BC, BLOCK, 0, stream>>>(
        X,
        wih[0], whh[0], bih[0], bhh[0],
        wih[1], whh[1], bih[1], bhh[1],
        wih[2], whh[2], bih[2], bhh[2],
        wih[3], whh[3], bih[3], bhh[3],
        wih[4], whh[4], bih[4], bhh[4],
        wout, bout,
        (float*)d_out);
}

// Round 8
// 875.064 us; speedup vs baseline: 1.7137x; 1.7137x over previous
//
#include <hip/hip_runtime.h>

#define T_STEPS 512
#define BC      4       // batch columns per block
#define BLOCK   512
#define GATEB   896     // gate region base (float index into sm)

// ---------------------------------------------------------------------------
// Layer-skewed pipeline, two-phase (R5 structure) + DPP butterfly, hedged.
//
// R7 failed with a container error (no counters). Hedge vs R7: keep
// v_add_f32_dpp quad_perm for xor1/xor2 (rocPRIM-standard idiom, moves 288
// of 336 LDS-pipe shuffle ops to the VALU pipe) but revert xor4 to the
// PROVEN __shfl_xor (ds_bpermute) path -- it only runs on the 2 ih0 waves
// (~48 wave-ops/tick, negligible). Everything else byte-identical to the
// verified R5 kernel. If this also dies, update_dpp is implicated; fallback
// is pure-shfl recursive halving.
//
// R5 model: tick 4660cy, LDS pipe ~2720cy (64 ds_read_b128 + 336
// ds_bpermute shuffles), rest latency at 2 waves/SIMD. DPP cuts LDS pipe
// to ~1300cy and shortens the reduce dependency chain.
//
// Exec-mask safety for DPP: every quad partner (lane^1, lane^2) is in the
// same section with the same act window (section boundaries quad-aligned;
// wave5 ih1/pool split at lane 48).
//
// Partition (unchanged from R5): 512 threads, every wave ONE gemm body:
//   arm   sections                 NJ  KC(rt)  tid        thr  cost
//   NJ6   ih0                      6   8       0-127      128  192   W0-W1
//         hh0                      6   4       128-191     64  192   W2
//         hh4                      6   4       192-255     64  192   W3
//   NJ4   out-proj                 4   4       256-319     64  128   W4
//         ih1                      4   4       320-367     48  128 \ W5
//         pool: ih4|hh3|hh1|ih2    4   2       368-511    144  128 /
//               |ih3|hh2 (K<=16, zero-padded)
//   x-prefetch: tid 448-511 (64 thr x 1 float4), commit in U phase.
//
// Zero-padded K: pool sections read h rows beyond true K; those rows are
// zeroed at init and never written (upd writes h<H only); load_w zeroes the
// matching weights.
//
// LDS: inv reads ke = k0 + (kk^kci); gate rows at gsw(row)=row^((row>>3)&7)
// (16B-granule XOR, bijective within sections).
// Gate rows: gi0:0 gh0:96 gi1:192 gh1:240 gi2:288 gh2:312 gi3:336 gh3:384
//            gi4:432 gh4:528  (624 rows x 4 floats)
// sm layout (floats): inv0[256] | hbuf 5x128 @256 | gate 2496 @896 = 3392
// ---------------------------------------------------------------------------

__device__ __forceinline__ int gsw(int row) { return row ^ ((row >> 3) & 7); }

__device__ __forceinline__ float sigmoid_f(float x) {
    return 1.0f / (1.0f + __expf(-x));
}
__device__ __forceinline__ float tanh_f(float x) {
    return 1.0f - 2.0f / (__expf(2.0f * x) + 1.0f);
}

// Cross-lane reduce steps. xor1/xor2 via DPP quad_perm = VALU pipe (no LDS):
// quad_perm[1,0,3,2] = 0xB1 ; quad_perm[2,3,0,1] = 0x4E. The x+update_dpp(x)
// pattern fuses to a single v_add_f32_dpp.
__device__ __forceinline__ float red_xor1(float x) {
    return x + __int_as_float(__builtin_amdgcn_update_dpp(
        0, __float_as_int(x), 0xB1, 0xF, 0xF, true));
}
__device__ __forceinline__ float red_xor2(float x) {
    return x + __int_as_float(__builtin_amdgcn_update_dpp(
        0, __float_as_int(x), 0x4E, 0xF, 0xF, true));
}
// xor4 via the PROVEN __shfl_xor path (ds_bpermute); ih0 waves only.
__device__ __forceinline__ float red_xor4(float x) {
    return x + __shfl_xor(x, 4, 64);
}

// Weight slice -> registers. COMPILE-TIME loop bounds only (rule #20).
// Kd = true K (also the row stride); ke >= Kd loads 0 (zero-padded K).
template<int NJ>
__device__ __forceinline__ void load_w(float (&wr)[48], float (&bs)[6],
                                       const float* __restrict__ Wp,
                                       const float* __restrict__ bp,
                                       int row0, int Kd, int k0, int cswz)
{
#pragma unroll
    for (int j = 0; j < NJ; ++j) {
        bs[j] = bp[row0 + j];
#pragma unroll
        for (int kk = 0; kk < 8; ++kk) {
            const int ke = k0 + (kk ^ cswz);
            wr[j * 8 + kk] = (ke < Kd) ? Wp[(row0 + j) * Kd + ke] : 0.0f;
        }
    }
}

// Gate-GEMM: NJ compile-time, KC runtime (guarded fixed-pattern reduce).
template<int NJ>
__device__ __forceinline__ void gemm_g(const float (&wr)[48], const float (&bs)[6],
                                       int kci, int cswz, int k0, int KC,
                                       float* __restrict__ sm, int inb,
                                       const int (&gwa)[6])
{
    float acc[NJ][4];
#pragma unroll
    for (int j = 0; j < NJ; ++j) {
        const float bj = (kci == 0) ? bs[j] : 0.0f;
#pragma unroll
        for (int b = 0; b < 4; ++b) acc[j][b] = bj;
    }
#pragma unroll
    for (int kk = 0; kk < 8; ++kk) {
        const int ke = k0 + (kk ^ cswz);
        const float4 v = *(const float4*)&sm[inb + ke * 4];
#pragma unroll
        for (int j = 0; j < NJ; ++j) {
            const float w = wr[j * 8 + kk];
            acc[j][0] = fmaf(w, v.x, acc[j][0]);
            acc[j][1] = fmaf(w, v.y, acc[j][1]);
            acc[j][2] = fmaf(w, v.z, acc[j][2]);
            acc[j][3] = fmaf(w, v.w, acc[j][3]);
        }
    }
    // butterfly: DPP (VALU) for xor1/xor2; ds_bpermute only for xor4 (ih0).
    // guards diverge but partners of any active lane share its KC.
    if (KC > 1) {
#pragma unroll
        for (int j = 0; j < NJ; ++j) {
            acc[j][0] = red_xor1(acc[j][0]);
            acc[j][1] = red_xor1(acc[j][1]);
            acc[j][2] = red_xor1(acc[j][2]);
            acc[j][3] = red_xor1(acc[j][3]);
        }
    }
    if (KC > 2) {
#pragma unroll
        for (int j = 0; j < NJ; ++j) {
            acc[j][0] = red_xor2(acc[j][0]);
            acc[j][1] = red_xor2(acc[j][1]);
            acc[j][2] = red_xor2(acc[j][2]);
            acc[j][3] = red_xor2(acc[j][3]);
        }
    }
    if (KC > 4) {
#pragma unroll
        for (int j = 0; j < NJ; ++j) {
            acc[j][0] = red_xor4(acc[j][0]);
            acc[j][1] = red_xor4(acc[j][1]);
            acc[j][2] = red_xor4(acc[j][2]);
            acc[j][3] = red_xor4(acc[j][3]);
        }
    }
    if (kci == 0) {
#pragma unroll
        for (int j = 0; j < NJ; ++j) {
            float4 o = {acc[j][0], acc[j][1], acc[j][2], acc[j][3]};
            *(float4*)&sm[gwa[j]] = o;
        }
    }
}

// Output projection: NJ=4, KC=4 fixed, writes global.
__device__ __forceinline__ void out_g(const float (&wr)[48], const float (&bs)[6],
                                      int kci, int cswz, int k0,
                                      const float* __restrict__ sm, int inb, int row0,
                                      float* __restrict__ outp)
{
    float acc[4][4];
#pragma unroll
    for (int j = 0; j < 4; ++j) {
        const float bj = (kci == 0) ? bs[j] : 0.0f;
#pragma unroll
        for (int b = 0; b < 4; ++b) acc[j][b] = bj;
    }
#pragma unroll
    for (int kk = 0; kk < 8; ++kk) {
        const int ke = k0 + (kk ^ cswz);
        const float4 v = *(const float4*)&sm[inb + ke * 4];
#pragma unroll
        for (int j = 0; j < 4; ++j) {
            const float w = wr[j * 8 + kk];
            acc[j][0] = fmaf(w, v.x, acc[j][0]);
            acc[j][1] = fmaf(w, v.y, acc[j][1]);
            acc[j][2] = fmaf(w, v.z, acc[j][2]);
            acc[j][3] = fmaf(w, v.w, acc[j][3]);
        }
    }
#pragma unroll
    for (int j = 0; j < 4; ++j) {
        acc[j][0] = red_xor1(acc[j][0]); acc[j][1] = red_xor1(acc[j][1]);
        acc[j][2] = red_xor1(acc[j][2]); acc[j][3] = red_xor1(acc[j][3]);
    }
#pragma unroll
    for (int j = 0; j < 4; ++j) {
        acc[j][0] = red_xor2(acc[j][0]); acc[j][1] = red_xor2(acc[j][1]);
        acc[j][2] = red_xor2(acc[j][2]); acc[j][3] = red_xor2(acc[j][3]);
    }
    if (kci == 0) {
#pragma unroll
        for (int b = 0; b < 4; ++b) {
            float4 o = {acc[0][b], acc[1][b], acc[2][b], acc[3][b]};
            *(float4*)&outp[(size_t)b * (T_STEPS * 64) + row0] = o;
        }
    }
}

__global__ __launch_bounds__(BLOCK, 2)
void gru_kernel(const float* __restrict__ X,
                const float* wih0, const float* whh0, const float* bih0, const float* bhh0,
                const float* wih1, const float* whh1, const float* bih1, const float* bhh1,
                const float* wih2, const float* whh2, const float* bih2, const float* bhh2,
                const float* wih3, const float* whh3, const float* bih3, const float* bhh3,
                const float* wih4, const float* whh4, const float* bih4, const float* bhh4,
                const float* wout, const float* bout,
                float* __restrict__ out)
{
    __shared__ __align__(16) float sm[3392];

    const int tid = threadIdx.x;
    const int b0  = blockIdx.x * BC;

    float wr[48];
    float bs[6];

    // ---- per-lane G-phase parameters ----
    int kci = 0, KC = 1, inb = 0, growA = 0, lo = 1, hi = 0, row0 = 0, Kd = 8;
    const float* Wp = nullptr; const float* bp = nullptr;

    if (tid < 128) {                      // ih0: NJ6, KC8, K=64, input x
        kci = tid & 7; KC = 8; row0 = (tid >> 3) * 6; Kd = 64;
        inb = 0; growA = 0 + row0; lo = 0; hi = 511; Wp = wih0; bp = bih0;
    } else if (tid < 192) {               // hh0: NJ6, KC4, K=32, input h0
        const int l = tid - 128; kci = l & 3; KC = 4; row0 = (l >> 2) * 6; Kd = 32;
        inb = 256; growA = 96 + row0; lo = 0; hi = 511; Wp = whh0; bp = bhh0;
    } else if (tid < 256) {               // hh4: NJ6, KC4, K=32, input h4
        const int l = tid - 192; kci = l & 3; KC = 4; row0 = (l >> 2) * 6; Kd = 32;
        inb = 768; growA = 528 + row0; lo = 4; hi = 515; Wp = whh4; bp = bhh4;
    } else if (tid < 320) {               // out-proj: NJ4, KC4, K=32, input h4
        const int l = tid - 256; kci = l & 3; KC = 4; row0 = (l >> 2) * 4; Kd = 32;
        inb = 768; lo = 5; hi = 516; Wp = wout; bp = bout;
    } else if (tid < 368) {               // ih1: NJ4, KC4, K=32, input h0
        const int l = tid - 320; kci = l & 3; KC = 4; row0 = (l >> 2) * 4; Kd = 32;
        inb = 256; growA = 192 + row0; lo = 1; hi = 512; Wp = wih1; bp = bih1;
    } else {                              // pool: NJ4, KC2, K<=16 zero-padded
        const int l = tid - 368; kci = l & 1; KC = 2;
        const int rg = l >> 1;            // rg in [0,72), 4 rows each
        if (rg < 24)      { row0 = rg * 4;        Wp = wih4; bp = bih4; Kd = 16;
                            inb = 640; growA = 432 + row0; lo = 4; hi = 515; }
        else if (rg < 36) { row0 = (rg - 24) * 4; Wp = whh3; bp = bhh3; Kd = 16;
                            inb = 640; growA = 384 + row0; lo = 3; hi = 514; }
        else if (rg < 48) { row0 = (rg - 36) * 4; Wp = whh1; bp = bhh1; Kd = 16;
                            inb = 384; growA = 240 + row0; lo = 1; hi = 512; }
        else if (rg < 54) { row0 = (rg - 48) * 4; Wp = wih2; bp = bih2; Kd = 16;
                            inb = 384; growA = 288 + row0; lo = 2; hi = 513; }
        else if (rg < 66) { row0 = (rg - 54) * 4; Wp = wih3; bp = bih3; Kd = 8;
                            inb = 512; growA = 336 + row0; lo = 3; hi = 514; }
        else              { row0 = (rg - 66) * 4; Wp = whh2; bp = bhh2; Kd = 8;
                            inb = 512; growA = 312 + row0; lo = 2; hi = 513; }
    }
    const int cswz = kci;
    const int k0   = kci * 8;

    // ---- weight slices into registers (compile-time-indexed stores only) ----
    if (tid < 256) load_w<6>(wr, bs, Wp, bp, row0, Kd, k0, cswz);
    else           load_w<4>(wr, bs, Wp, bp, row0, Kd, k0, cswz);

    // ---- precomputed swizzled gate-write addresses ----
    int gwa[6];
#pragma unroll
    for (int j = 0; j < 6; ++j) gwa[j] = GATEB + gsw(growA + j) * 4;

    // ---- per-lane U-phase parameters ----
    int a_ir = 0, a_iz = 0, a_in = 0, a_hr = 0, a_hz = 0, a_hn = 0, hoff = 0;
    int ulo = 1, uhi = 0;
    if (tid < 416) {
        int l, h; const int b = tid & 3;
        if      (tid < 128) { l = 0; h = tid >> 2; }
        else if (tid < 192) { l = 1; h = (tid - 128) >> 2; }
        else if (tid < 224) { l = 2; h = (tid - 192) >> 2; }
        else if (tid < 288) { l = 3; h = (tid - 224) >> 2; }
        else                { l = 4; h = (tid - 288) >> 2; }
        int giB, ghB, H;
        if      (l == 0) { giB = 0;   ghB = 96;  H = 32; }
        else if (l == 1) { giB = 192; ghB = 240; H = 16; }
        else if (l == 2) { giB = 288; ghB = 312; H = 8;  }
        else if (l == 3) { giB = 336; ghB = 384; H = 16; }
        else             { giB = 432; ghB = 528; H = 32; }
        a_ir = GATEB + gsw(giB + h) * 4 + b;
        a_iz = GATEB + gsw(giB + H + h) * 4 + b;
        a_in = GATEB + gsw(giB + 2 * H + h) * 4 + b;
        a_hr = GATEB + gsw(ghB + h) * 4 + b;
        a_hz = GATEB + gsw(ghB + H + h) * 4 + b;
        a_hn = GATEB + gsw(ghB + 2 * H + h) * 4 + b;
        hoff = 256 + l * 128 + h * 4 + b;
        ulo = l; uhi = 511 + l;
    }

    // ---- init: zero h states (incl. padding rows), stage x(0) ----
    for (int i = 256 + tid; i < GATEB; i += BLOCK) sm[i] = 0.0f;
    if (tid >= 448) {
        const int e = tid - 448, xb = e & 3, xd0 = (e >> 2) << 2;
        const float4 v = *(const float4*)&X[(size_t)(b0 + xb) * (T_STEPS * 64) + xd0];
        sm[(xd0 + 0) * 4 + xb] = v.x; sm[(xd0 + 1) * 4 + xb] = v.y;
        sm[(xd0 + 2) * 4 + xb] = v.z; sm[(xd0 + 3) * 4 + xb] = v.w;
    }
    __syncthreads();

    float4 xr = {0.f, 0.f, 0.f, 0.f};

    for (int tau = 0; tau < T_STEPS + 5; ++tau) {
        const bool act = (tau >= lo) && (tau <= hi);
        // ================= G phase =================
        if (tid < 256) {
            if (act) gemm_g<6>(wr, bs, kci, cswz, k0, KC, sm, inb, gwa);
        } else if (tid < 320) {
            if (act) out_g(wr, bs, kci, cswz, k0, sm, inb, row0,
                           out + ((size_t)b0 * T_STEPS + (tau - 5)) * 64);
        } else {
            if (tid >= 448 && tau + 1 < T_STEPS) {   // x(tau+1) prefetch
                const int e = tid - 448, xb = e & 3, xd0 = (e >> 2) << 2;
                xr = *(const float4*)&X[((size_t)(b0 + xb) * T_STEPS + (tau + 1)) * 64 + xd0];
            }
            if (act) gemm_g<4>(wr, bs, kci, cswz, k0, KC, sm, inb, gwa);
        }
        __syncthreads();
        // ================= U phase =================
        if (tid < 416 && tau >= ulo && tau <= uhi) {
            const float r = sigmoid_f(sm[a_ir] + sm[a_hr]);
            const float z = sigmoid_f(sm[a_iz] + sm[a_hz]);
            const float n = tanh_f(sm[a_in] + r * sm[a_hn]);
            sm[hoff] = (1.0f - z) * n + z * sm[hoff];
        }
        if (tid >= 448 && tau + 1 < T_STEPS) {       // commit x(tau+1)
            const int e = tid - 448, xb = e & 3, xd0 = (e >> 2) << 2;
            sm[(xd0 + 0) * 4 + xb] = xr.x; sm[(xd0 + 1) * 4 + xb] = xr.y;
            sm[(xd0 + 2) * 4 + xb] = xr.z; sm[(xd0 + 3) * 4 + xb] = xr.w;
        }
        __syncthreads();
    }
}

extern "C" void kernel_launch(void* const* d_in, const int* in_sizes, int n_in,
                              void* d_out, int out_size, void* d_ws, size_t ws_size,
                              hipStream_t stream)
{
    const float* X = (const float*)d_in[0];
    const float* wih[5]; const float* whh[5]; const float* bih[5]; const float* bhh[5];
    for (int l = 0; l < 5; ++l) {
        wih[l] = (const float*)d_in[1 + 4 * l];
        whh[l] = (const float*)d_in[2 + 4 * l];
        bih[l] = (const float*)d_in[3 + 4 * l];
        bhh[l] = (const float*)d_in[4 + 4 * l];
    }
    const float* wout = (const float*)d_in[21];
    const float* bout = (const float*)d_in[22];

    gru_kernel<<<1024 / BC, BLOCK, 0, stream>>>(
        X,
        wih[0], whh[0], bih[0], bhh[0],
        wih[1], whh[1], bih[1], bhh[1],
        wih[2], whh[2], bih[2], bhh[2],
        wih[3], whh[3], bih[3], bhh[3],
        wih[4], whh[4], bih[4], bhh[4],
        wout, bout,
        (float*)d_out);
}